// Round 7
// baseline (2732.828 us; speedup 1.0000x reference)
//
#include <hip/hip_runtime.h>
#include <math.h>

#define N_NODES 100000
#define E_EDGES 1600000
#define HALF_E  (E_EDGES / 2)
#define SCAN_CHUNK 4096
#define NB_SCAN ((N_NODES + SCAN_CHUNK - 1) / SCAN_CHUNK)

#define NBUCK 256
#define ROWS_PER_BUCKET ((N_NODES + NBUCK - 1) / NBUCK)   // 391
#define EDGES_PER_BLK_A 4096
#define NBLK_A ((E_EDGES + EDGES_PER_BLK_A - 1) / EDGES_PER_BLK_A)  // 391

typedef unsigned short ushort_t;

// ---- bf16 helpers (RNE pack, cheap unpack) ----
__device__ __forceinline__ unsigned bf16_1(float f) {
    unsigned u = __float_as_uint(f);
    return (u + 0x7fffu + ((u >> 16) & 1u)) >> 16;
}
__device__ __forceinline__ unsigned bf16_2(float a, float b) {
    return bf16_1(a) | (bf16_1(b) << 16);
}
__device__ __forceinline__ float bf16_f(ushort_t us) {
    return __uint_as_float(((unsigned)us) << 16);
}

// ============ CSR build ============

__global__ __launch_bounds__(256) void k_hist(const int* __restrict__ rowIdx,
                                              int* __restrict__ cnt) {
    int e = blockIdx.x * 256 + threadIdx.x;
    if (e < E_EDGES) atomicAdd(&cnt[rowIdx[e]], 1);
}

__global__ __launch_bounds__(256) void k_bsum(const int* __restrict__ cnt,
                                              int* __restrict__ bsum) {
    __shared__ int lds[256];
    const int tid = threadIdx.x;
    int base = blockIdx.x * SCAN_CHUNK + tid * 16;
    int s = 0;
#pragma unroll
    for (int i = 0; i < 16; ++i) {
        int idx = base + i;
        if (idx < N_NODES) s += cnt[idx];
    }
    lds[tid] = s;
    __syncthreads();
    for (int st = 128; st > 0; st >>= 1) {
        if (tid < st) lds[tid] += lds[tid + st];
        __syncthreads();
    }
    if (tid == 0) bsum[blockIdx.x] = lds[0];
}

__global__ __launch_bounds__(64) void k_bscan(int* __restrict__ bsum,
                                              int* __restrict__ start) {
    if (threadIdx.x == 0) {
        int run = 0;
        for (int i = 0; i < NB_SCAN; ++i) {
            int t = bsum[i];
            bsum[i] = run;
            run += t;
        }
        start[N_NODES] = E_EDGES;
    }
}

__global__ __launch_bounds__(256) void k_starts(const int* __restrict__ cnt,
                                                const int* __restrict__ bsum,
                                                int* __restrict__ start) {
    __shared__ int lds[256];
    const int tid = threadIdx.x;
    int base = blockIdx.x * SCAN_CHUNK + tid * 16;
    int vals[16];
    int s = 0;
#pragma unroll
    for (int i = 0; i < 16; ++i) {
        int idx = base + i;
        int v = (idx < N_NODES) ? cnt[idx] : 0;
        vals[i] = v;
        s += v;
    }
    lds[tid] = s;
    __syncthreads();
    for (int st = 1; st < 256; st <<= 1) {
        int t = (tid >= st) ? lds[tid - st] : 0;
        __syncthreads();
        lds[tid] += t;
        __syncthreads();
    }
    int run = bsum[blockIdx.x] + lds[tid] - s;
#pragma unroll
    for (int i = 0; i < 16; ++i) {
        int idx = base + i;
        if (idx < N_NODES) { start[idx] = run; run += vals[i]; }
    }
}

__global__ __launch_bounds__(256) void k_initcur(const int* __restrict__ start,
                                                 int* __restrict__ cursorA) {
    int b = threadIdx.x;
    cursorA[b] = start[b * ROWS_PER_BUCKET];
}

__global__ __launch_bounds__(256) void k_bucketA(const int* __restrict__ rowIdx,
                                                 const int* __restrict__ colIdx,
                                                 int* __restrict__ cursorA,
                                                 uint2* __restrict__ pairs) {
    __shared__ uint2 stage[EDGES_PER_BLK_A];
    __shared__ unsigned char bmap[EDGES_PER_BLK_A];
    __shared__ int cntL[NBUCK], scanEx[NBUCK], cur[NBUCK], posG[NBUCK];
    const int tid = threadIdx.x;
    const int e0 = blockIdx.x * EDGES_PER_BLK_A;
    const int n = min(EDGES_PER_BLK_A, E_EDGES - e0);

    cntL[tid] = 0;
    __syncthreads();
    for (int i = tid; i < n; i += 256) {
        int b = rowIdx[e0 + i] / ROWS_PER_BUCKET;
        atomicAdd(&cntL[b], 1);
    }
    __syncthreads();
    int myc = cntL[tid];
    scanEx[tid] = myc;
    __syncthreads();
    for (int st = 1; st < 256; st <<= 1) {
        int t = (tid >= st) ? scanEx[tid - st] : 0;
        __syncthreads();
        scanEx[tid] += t;
        __syncthreads();
    }
    int ex = scanEx[tid] - myc;
    __syncthreads();
    scanEx[tid] = ex;
    cur[tid] = ex;
    if (myc) posG[tid] = atomicAdd(&cursorA[tid], myc);
    __syncthreads();
    for (int i = tid; i < n; i += 256) {
        int r = rowIdx[e0 + i];
        int c = colIdx[e0 + i];
        int b = r / ROWS_PER_BUCKET;
        int slot = atomicAdd(&cur[b], 1);
        stage[slot] = make_uint2((unsigned)c, (unsigned)r);
        bmap[slot] = (unsigned char)b;
    }
    __syncthreads();
    for (int i = tid; i < n; i += 256) {
        int b = bmap[i];
        int dst = posG[b] + (i - scanEx[b]);
        pairs[dst] = stage[i];
    }
}

__global__ __launch_bounds__(256) void k_bucketB(const int* __restrict__ start,
                                                 const uint2* __restrict__ pairs,
                                                 int* __restrict__ csr) {
    __shared__ int cur[ROWS_PER_BUCKET];
    const int tid = threadIdx.x;
    const int rowbase = blockIdx.x * ROWS_PER_BUCKET;
    const int nrows = min(ROWS_PER_BUCKET, N_NODES - rowbase);
    for (int i = tid; i < nrows; i += 256) cur[i] = start[rowbase + i];
    __syncthreads();
    const int bBeg = start[rowbase];
    const int bEnd = start[rowbase + nrows];
    for (int i = bBeg + tid; i < bEnd; i += 256) {
        uint2 p = pairs[i];
        int pos = atomicAdd(&cur[(int)p.y - rowbase], 1);
        csr[pos] = (int)p.x;
    }
}

// ============ fused node MLPs: 4 threads per row, 16 outputs each ============
// Block = 256 thr = 64 rows. __launch_bounds__(256,4) caps VGPR at 128 -> 4 waves/SIMD.
// Weights read as float4 quads; intermediates shared via LDS [64][68].

#define SH_STRIDE 68

#define FMA16(xk, w0, w1, w2, w3, o)                                          \
    o[0] = fmaf(xk, w0.x, o[0]);  o[1] = fmaf(xk, w0.y, o[1]);                \
    o[2] = fmaf(xk, w0.z, o[2]);  o[3] = fmaf(xk, w0.w, o[3]);                \
    o[4] = fmaf(xk, w1.x, o[4]);  o[5] = fmaf(xk, w1.y, o[5]);                \
    o[6] = fmaf(xk, w1.z, o[6]);  o[7] = fmaf(xk, w1.w, o[7]);                \
    o[8] = fmaf(xk, w2.x, o[8]);  o[9] = fmaf(xk, w2.y, o[9]);                \
    o[10] = fmaf(xk, w2.z, o[10]); o[11] = fmaf(xk, w2.w, o[11]);             \
    o[12] = fmaf(xk, w3.x, o[12]); o[13] = fmaf(xk, w3.y, o[13]);             \
    o[14] = fmaf(xk, w3.z, o[14]); o[15] = fmaf(xk, w3.w, o[15]);

// o[16] += row(K=64 from LDS) @ w[64][64] column chunk (wc = w + co)
__device__ __forceinline__ void gemm16_lds(const float* __restrict__ row,
                                           const float* __restrict__ wc,
                                           float o[16]) {
#pragma unroll 4
    for (int k4 = 0; k4 < 16; ++k4) {
        float4 v = *(const float4*)(row + k4 * 4);
#pragma unroll
        for (int kk = 0; kk < 4; ++kk) {
            float xk = (&v.x)[kk];
            const float4* wr = (const float4*)(wc + (k4 * 4 + kk) * 64);
            float4 w0 = wr[0], w1 = wr[1], w2 = wr[2], w3 = wr[3];
            FMA16(xk, w0, w1, w2, w3, o)
        }
    }
}

// o[16] += vrow(float4 stream, K4 quads) @ w column chunk, optional scale on x
__device__ __forceinline__ void gemm16_g(const float4* __restrict__ xv,
                                         const float* __restrict__ wc,
                                         float o[16], int K4, bool valid, float scale) {
#pragma unroll 4
    for (int k4 = 0; k4 < K4; ++k4) {
        float4 v = valid ? xv[k4] : make_float4(0.f, 0.f, 0.f, 0.f);
#pragma unroll
        for (int kk = 0; kk < 4; ++kk) {
            float xk = (&v.x)[kk] * scale;
            const float4* wr = (const float4*)(wc + (k4 * 4 + kk) * 64);
            float4 w0 = wr[0], w1 = wr[1], w2 = wr[2], w3 = wr[3];
            FMA16(xk, w0, w1, w2, w3, o)
        }
    }
}

__device__ __forceinline__ void sh_store16(float* dst, const float o[16]) {
    *(float4*)(dst + 0)  = make_float4(o[0], o[1], o[2], o[3]);
    *(float4*)(dst + 4)  = make_float4(o[4], o[5], o[6], o[7]);
    *(float4*)(dst + 8)  = make_float4(o[8], o[9], o[10], o[11]);
    *(float4*)(dst + 12) = make_float4(o[12], o[13], o[14], o[15]);
}

// h = x@w_in+b_in ; msg16 = relu(relu(h@m1+b1)@m2+b2)
__global__ __launch_bounds__(256, 4) void k_lin_msg(const float* __restrict__ x,
                                                    const float* __restrict__ w,
                                                    const float* __restrict__ b,
                                                    const float* __restrict__ m1w,
                                                    const float* __restrict__ m1b,
                                                    const float* __restrict__ m2w,
                                                    const float* __restrict__ m2b,
                                                    float* __restrict__ h,
                                                    ushort_t* __restrict__ msg16) {
    __shared__ float sh[64][SH_STRIDE];
    const int tid = threadIdx.x;
    const int rowL = tid >> 2;
    const int sub = tid & 3;
    const int co = sub * 16;
    const int r = blockIdx.x * 64 + rowL;
    const bool valid = r < N_NODES;

    float o[16];
#pragma unroll
    for (int j = 0; j < 16; ++j) o[j] = b[co + j];
    gemm16_g((const float4*)(x + (size_t)r * 128), w + co, o, 32, valid, 1.0f);
    if (valid) {
        float4* hw = (float4*)(h + (size_t)r * 64 + co);
        hw[0] = make_float4(o[0], o[1], o[2], o[3]);
        hw[1] = make_float4(o[4], o[5], o[6], o[7]);
        hw[2] = make_float4(o[8], o[9], o[10], o[11]);
        hw[3] = make_float4(o[12], o[13], o[14], o[15]);
    }
    sh_store16(&sh[rowL][co], o);
    __syncthreads();

    float t[16];
#pragma unroll
    for (int j = 0; j < 16; ++j) t[j] = m1b[co + j];
    gemm16_lds(sh[rowL], m1w + co, t);
#pragma unroll
    for (int j = 0; j < 16; ++j) t[j] = fmaxf(t[j], 0.0f);
    __syncthreads();
    sh_store16(&sh[rowL][co], t);
    __syncthreads();

#pragma unroll
    for (int j = 0; j < 16; ++j) o[j] = m2b[co + j];
    gemm16_lds(sh[rowL], m2w + co, o);
    if (valid) {
        uint4* mv = (uint4*)(msg16 + (size_t)r * 64 + co);
        mv[0] = make_uint4(bf16_2(fmaxf(o[0], 0.f), fmaxf(o[1], 0.f)),
                           bf16_2(fmaxf(o[2], 0.f), fmaxf(o[3], 0.f)),
                           bf16_2(fmaxf(o[4], 0.f), fmaxf(o[5], 0.f)),
                           bf16_2(fmaxf(o[6], 0.f), fmaxf(o[7], 0.f)));
        mv[1] = make_uint4(bf16_2(fmaxf(o[8], 0.f), fmaxf(o[9], 0.f)),
                           bf16_2(fmaxf(o[10], 0.f), fmaxf(o[11], 0.f)),
                           bf16_2(fmaxf(o[12], 0.f), fmaxf(o[13], 0.f)),
                           bf16_2(fmaxf(o[14], 0.f), fmaxf(o[15], 0.f)));
    }
}

// ============ aggregation: gather (wave per node, bf16 msg) ============
__global__ __launch_bounds__(256) void k_gather(const int* __restrict__ start,
                                                const int* __restrict__ csr,
                                                const ushort_t* __restrict__ msg16,
                                                float* __restrict__ agg) {
    const int lane = threadIdx.x & 63;
    const int wid  = threadIdx.x >> 6;
    int r = blockIdx.x * 4 + wid;
    if (r >= N_NODES) return;
    int b = start[r];
    int e0 = start[r + 1];
    float acc0 = 0.0f, acc1 = 0.0f;
    for (int base = b; base < e0; base += 64) {
        int n = e0 - base;
        if (n > 64) n = 64;
        int c = 0;
        if (base + lane < e0) c = csr[base + lane];
        int j = 0;
        for (; j + 4 <= n; j += 4) {
            int c0 = __shfl(c, j, 64);
            int c1 = __shfl(c, j + 1, 64);
            int c2 = __shfl(c, j + 2, 64);
            int c3 = __shfl(c, j + 3, 64);
            float l0 = bf16_f(msg16[(size_t)c0 * 64 + lane]);
            float l1 = bf16_f(msg16[(size_t)c1 * 64 + lane]);
            float l2 = bf16_f(msg16[(size_t)c2 * 64 + lane]);
            float l3 = bf16_f(msg16[(size_t)c3 * 64 + lane]);
            acc0 += l0 + l2;
            acc1 += l1 + l3;
        }
        for (; j < n; ++j) {
            int cj = __shfl(c, j, 64);
            acc0 += bf16_f(msg16[(size_t)cj * 64 + lane]);
        }
    }
    agg[(size_t)r * 64 + lane] = acc0 + acc1;
}

// ---- update layer0 then msg layer1, fused (4 thr/row) ----
__global__ __launch_bounds__(256, 4) void k_update_msg(float* __restrict__ h,
                                                       const float* __restrict__ agg,
                                                       const int* __restrict__ cnt,
                                                       const float* __restrict__ u1,
                                                       const float* __restrict__ b1,
                                                       const float* __restrict__ u2,
                                                       const float* __restrict__ b2,
                                                       const float* __restrict__ m1w,
                                                       const float* __restrict__ m1b,
                                                       const float* __restrict__ m2w,
                                                       const float* __restrict__ m2b,
                                                       ushort_t* __restrict__ msg16) {
    __shared__ float sh[64][SH_STRIDE];
    const int tid = threadIdx.x;
    const int rowL = tid >> 2;
    const int sub = tid & 3;
    const int co = sub * 16;
    const int r = blockIdx.x * 64 + rowL;
    const bool valid = r < N_NODES;

    float t[16];
#pragma unroll
    for (int j = 0; j < 16; ++j) t[j] = b1[co + j];
    gemm16_g((const float4*)(h + (size_t)r * 64), u1 + co, t, 16, valid, 1.0f);
    float inv = valid ? (1.0f / fmaxf((float)cnt[r], 1.0f)) : 0.0f;
    gemm16_g((const float4*)(agg + (size_t)r * 64), u1 + 64 * 64 + co, t, 16, valid, inv);
#pragma unroll
    for (int j = 0; j < 16; ++j) t[j] = fmaxf(t[j], 0.0f);
    sh_store16(&sh[rowL][co], t);
    __syncthreads();

    float o[16];
#pragma unroll
    for (int j = 0; j < 16; ++j) o[j] = b2[co + j];
    gemm16_lds(sh[rowL], u2 + co, o);
    if (valid) {
        const float4* hres = (const float4*)(h + (size_t)r * 64 + co);
#pragma unroll
        for (int j4 = 0; j4 < 4; ++j4) {
            float4 v = hres[j4];
            o[4 * j4 + 0] += v.x;
            o[4 * j4 + 1] += v.y;
            o[4 * j4 + 2] += v.z;
            o[4 * j4 + 3] += v.w;
        }
        float4* hw = (float4*)(h + (size_t)r * 64 + co);
        hw[0] = make_float4(o[0], o[1], o[2], o[3]);
        hw[1] = make_float4(o[4], o[5], o[6], o[7]);
        hw[2] = make_float4(o[8], o[9], o[10], o[11]);
        hw[3] = make_float4(o[12], o[13], o[14], o[15]);
    }
    __syncthreads();
    sh_store16(&sh[rowL][co], o);
    __syncthreads();

#pragma unroll
    for (int j = 0; j < 16; ++j) t[j] = m1b[co + j];
    gemm16_lds(sh[rowL], m1w + co, t);
#pragma unroll
    for (int j = 0; j < 16; ++j) t[j] = fmaxf(t[j], 0.0f);
    __syncthreads();
    sh_store16(&sh[rowL][co], t);
    __syncthreads();

#pragma unroll
    for (int j = 0; j < 16; ++j) o[j] = m2b[co + j];
    gemm16_lds(sh[rowL], m2w + co, o);
    if (valid) {
        uint4* mv = (uint4*)(msg16 + (size_t)r * 64 + co);
        mv[0] = make_uint4(bf16_2(fmaxf(o[0], 0.f), fmaxf(o[1], 0.f)),
                           bf16_2(fmaxf(o[2], 0.f), fmaxf(o[3], 0.f)),
                           bf16_2(fmaxf(o[4], 0.f), fmaxf(o[5], 0.f)),
                           bf16_2(fmaxf(o[6], 0.f), fmaxf(o[7], 0.f)));
        mv[1] = make_uint4(bf16_2(fmaxf(o[8], 0.f), fmaxf(o[9], 0.f)),
                           bf16_2(fmaxf(o[10], 0.f), fmaxf(o[11], 0.f)),
                           bf16_2(fmaxf(o[12], 0.f), fmaxf(o[13], 0.f)),
                           bf16_2(fmaxf(o[14], 0.f), fmaxf(o[15], 0.f)));
    }
}

// ---- update layer1 then head precompute, fused (4 thr/row) ----
__global__ __launch_bounds__(256, 4) void k_update_headpre(const float* __restrict__ h,
                                                           const float* __restrict__ agg,
                                                           const int* __restrict__ cnt,
                                                           const float* __restrict__ u1,
                                                           const float* __restrict__ b1,
                                                           const float* __restrict__ u2,
                                                           const float* __restrict__ b2,
                                                           const float* __restrict__ hw1,
                                                           const float* __restrict__ hb1,
                                                           ushort_t* __restrict__ hA16,
                                                           ushort_t* __restrict__ hB16) {
    __shared__ float sh[64][SH_STRIDE];
    const int tid = threadIdx.x;
    const int rowL = tid >> 2;
    const int sub = tid & 3;
    const int co = sub * 16;
    const int r = blockIdx.x * 64 + rowL;
    const bool valid = r < N_NODES;

    float dv = valid ? (float)cnt[r] : 0.0f;
    float t[16];
#pragma unroll
    for (int j = 0; j < 16; ++j) t[j] = b1[co + j];
    gemm16_g((const float4*)(h + (size_t)r * 64), u1 + co, t, 16, valid, 1.0f);
    float inv = 1.0f / fmaxf(dv, 1.0f);
    gemm16_g((const float4*)(agg + (size_t)r * 64), u1 + 64 * 64 + co, t, 16, valid, inv);
#pragma unroll
    for (int j = 0; j < 16; ++j) t[j] = fmaxf(t[j], 0.0f);
    sh_store16(&sh[rowL][co], t);
    __syncthreads();

    float o[16];
#pragma unroll
    for (int j = 0; j < 16; ++j) o[j] = b2[co + j];
    gemm16_lds(sh[rowL], u2 + co, o);
    if (valid) {
        const float4* hres = (const float4*)(h + (size_t)r * 64 + co);
#pragma unroll
        for (int j4 = 0; j4 < 4; ++j4) {
            float4 v = hres[j4];
            o[4 * j4 + 0] += v.x;
            o[4 * j4 + 1] += v.y;
            o[4 * j4 + 2] += v.z;
            o[4 * j4 + 3] += v.w;
        }
    }
    __syncthreads();
    sh_store16(&sh[rowL][co], o);
    __syncthreads();

    // headpre A
#pragma unroll
    for (int j = 0; j < 16; ++j) t[j] = hb1[co + j] + dv * hw1[128 * 64 + co + j];
    gemm16_lds(sh[rowL], hw1 + co, t);
    if (valid) {
        uint4* ov = (uint4*)(hA16 + (size_t)r * 64 + co);
        ov[0] = make_uint4(bf16_2(t[0], t[1]), bf16_2(t[2], t[3]),
                           bf16_2(t[4], t[5]), bf16_2(t[6], t[7]));
        ov[1] = make_uint4(bf16_2(t[8], t[9]), bf16_2(t[10], t[11]),
                           bf16_2(t[12], t[13]), bf16_2(t[14], t[15]));
    }
    // headpre B
#pragma unroll
    for (int j = 0; j < 16; ++j) t[j] = dv * hw1[129 * 64 + co + j];
    gemm16_lds(sh[rowL], hw1 + 64 * 64 + co, t);
    if (valid) {
        uint4* ov = (uint4*)(hB16 + (size_t)r * 64 + co);
        ov[0] = make_uint4(bf16_2(t[0], t[1]), bf16_2(t[2], t[3]),
                           bf16_2(t[4], t[5]), bf16_2(t[6], t[7]));
        ov[1] = make_uint4(bf16_2(t[8], t[9]), bf16_2(t[10], t[11]),
                           bf16_2(t[12], t[13]), bf16_2(t[14], t[15]));
    }
}

// ------- out[e] = out[e+HALF] = softplus(relu(hA[src]+hB[dst]) . h2w + h2b) + 1e-6 ------
__global__ __launch_bounds__(256) void k_head(const int* __restrict__ rowIdx,
                                              const int* __restrict__ colIdx,
                                              const ushort_t* __restrict__ hA16,
                                              const ushort_t* __restrict__ hB16,
                                              const float* __restrict__ w2,
                                              const float* __restrict__ b2,
                                              float* __restrict__ out) {
    const int lane = threadIdx.x & 63;
    const int sub = lane & 15;
    const int grp = lane >> 4;
    const int waveId = (blockIdx.x * 256 + threadIdx.x) >> 6;
    const int step = gridDim.x * 4 * 4;
    const float4 wv = *(const float4*)(w2 + sub * 4);
    const float b2v = b2[0];
    for (int e = waveId * 4 + grp; e < HALF_E; e += step) {
        int s = rowIdx[e];
        int d = colIdx[e];
        ushort4 a4 = *(const ushort4*)(hA16 + (size_t)s * 64 + sub * 4);
        ushort4 b4 = *(const ushort4*)(hB16 + (size_t)d * 64 + sub * 4);
        float t0 = fmaxf(bf16_f(a4.x) + bf16_f(b4.x), 0.0f);
        float t1 = fmaxf(bf16_f(a4.y) + bf16_f(b4.y), 0.0f);
        float t2 = fmaxf(bf16_f(a4.z) + bf16_f(b4.z), 0.0f);
        float t3 = fmaxf(bf16_f(a4.w) + bf16_f(b4.w), 0.0f);
        float p = t0 * wv.x + t1 * wv.y + t2 * wv.z + t3 * wv.w;
        p += __shfl_xor(p, 1);
        p += __shfl_xor(p, 2);
        p += __shfl_xor(p, 4);
        p += __shfl_xor(p, 8);
        if (sub == 0) {
            float sv = p + b2v;
            float sp = fmaxf(sv, 0.0f) + log1pf(expf(-fabsf(sv)));
            float wvv = sp + 1e-6f;
            out[e] = wvv;
            out[e + HALF_E] = wvv;
        }
    }
}

extern "C" void kernel_launch(void* const* d_in, const int* in_sizes, int n_in,
                              void* d_out, int out_size, void* d_ws, size_t ws_size,
                              hipStream_t stream) {
    const float* x      = (const float*)d_in[0];
    const int*   rowIdx = (const int*)d_in[1];
    const int*   colIdx = rowIdx + E_EDGES;
    const float* w_in   = (const float*)d_in[2];
    const float* b_in   = (const float*)d_in[3];
    const float* l0_m1w = (const float*)d_in[4];
    const float* l0_m1b = (const float*)d_in[5];
    const float* l0_m2w = (const float*)d_in[6];
    const float* l0_m2b = (const float*)d_in[7];
    const float* l0_u1w = (const float*)d_in[8];
    const float* l0_u1b = (const float*)d_in[9];
    const float* l0_u2w = (const float*)d_in[10];
    const float* l0_u2b = (const float*)d_in[11];
    const float* l1_m1w = (const float*)d_in[12];
    const float* l1_m1b = (const float*)d_in[13];
    const float* l1_m2w = (const float*)d_in[14];
    const float* l1_m2b = (const float*)d_in[15];
    const float* l1_u1w = (const float*)d_in[16];
    const float* l1_u1b = (const float*)d_in[17];
    const float* l1_u2w = (const float*)d_in[18];
    const float* l1_u2b = (const float*)d_in[19];
    const float* h1w    = (const float*)d_in[20];
    const float* h1b    = (const float*)d_in[21];
    const float* h2w    = (const float*)d_in[22];
    const float* h2b    = (const float*)d_in[23];

    float* out = (float*)d_out;

    float*    h     = (float*)d_ws;                         // N x 64 f32
    float*    agg   = h + (size_t)N_NODES * 64;             // N x 64 f32
    ushort_t* msg16 = (ushort_t*)(agg + (size_t)N_NODES * 64); // N x 64 bf16
    ushort_t* hB16  = msg16 + (size_t)N_NODES * 64;         // N x 64 bf16
    int*      cnt   = (int*)(hB16 + (size_t)N_NODES * 64);  // N
    int*      start = cnt + N_NODES;                        // N + 1
    int*      bsum  = start + N_NODES + 1;                  // NB_SCAN (pad 32)
    int*      curA  = bsum + 32;                            // NBUCK
    int*      csr   = curA + NBUCK;                         // E
    uint2*    pairs = (uint2*)agg;                          // alias: dead before gather writes agg
    ushort_t* hA16  = msg16;                                // alias: msg16 dead after gather1

    const int nb64 = (N_NODES + 63) / 64;                   // 1563 blocks for MLP kernels
    const int edgeBlocks = (E_EDGES + 255) / 256;
    const int gatherBlocks = (N_NODES + 3) / 4;

    // ---- CSR build (bucket sort: coalesced writes) ----
    hipMemsetAsync(cnt, 0, (size_t)N_NODES * sizeof(int), stream);
    k_hist<<<edgeBlocks, 256, 0, stream>>>(rowIdx, cnt);
    k_bsum<<<NB_SCAN, 256, 0, stream>>>(cnt, bsum);
    k_bscan<<<1, 64, 0, stream>>>(bsum, start);
    k_starts<<<NB_SCAN, 256, 0, stream>>>(cnt, bsum, start);
    k_initcur<<<1, NBUCK, 0, stream>>>(start, curA);
    k_bucketA<<<NBLK_A, 256, 0, stream>>>(rowIdx, colIdx, curA, pairs);
    k_bucketB<<<NBUCK, 256, 0, stream>>>(start, pairs, csr);

    // ---- input linear + layer0 message (fused) ----
    k_lin_msg<<<nb64, 256, 0, stream>>>(x, w_in, b_in,
                                        l0_m1w, l0_m1b, l0_m2w, l0_m2b, h, msg16);
    // ---- layer 0 aggregate; update + layer1 message (fused) ----
    k_gather<<<gatherBlocks, 256, 0, stream>>>(start, csr, msg16, agg);
    k_update_msg<<<nb64, 256, 0, stream>>>(h, agg, cnt,
                                           l0_u1w, l0_u1b, l0_u2w, l0_u2b,
                                           l1_m1w, l1_m1b, l1_m2w, l1_m2b, msg16);
    // ---- layer 1 aggregate; update + head precompute (fused) ----
    k_gather<<<gatherBlocks, 256, 0, stream>>>(start, csr, msg16, agg);
    k_update_headpre<<<nb64, 256, 0, stream>>>(h, agg, cnt,
                                               l1_u1w, l1_u1b, l1_u2w, l1_u2b,
                                               h1w, h1b, hA16, hB16);
    // ---- head ----
    k_head<<<4096, 256, 0, stream>>>(rowIdx, colIdx, hA16, hB16, h2w, h2b, out);
}

// Round 8
// 454.965 us; speedup vs baseline: 6.0067x; 6.0067x over previous
//
#include <hip/hip_runtime.h>
#include <math.h>

#define N_NODES 100000
#define E_EDGES 1600000
#define HALF_E  (E_EDGES / 2)
#define SCAN_CHUNK 4096
#define NB_SCAN ((N_NODES + SCAN_CHUNK - 1) / SCAN_CHUNK)

#define NBUCK 256
#define ROWS_PER_BUCKET ((N_NODES + NBUCK - 1) / NBUCK)   // 391
#define EDGES_PER_BLK_A 4096
#define NBLK_A ((E_EDGES + EDGES_PER_BLK_A - 1) / EDGES_PER_BLK_A)  // 391

typedef unsigned short ushort_t;

// ---- bf16 helpers (RNE pack, cheap unpack) ----
__device__ __forceinline__ unsigned bf16_1(float f) {
    unsigned u = __float_as_uint(f);
    return (u + 0x7fffu + ((u >> 16) & 1u)) >> 16;
}
__device__ __forceinline__ unsigned bf16_2(float a, float b) {
    return bf16_1(a) | (bf16_1(b) << 16);
}
__device__ __forceinline__ float bf16_f(ushort_t us) {
    return __uint_as_float(((unsigned)us) << 16);
}

// ============ CSR build ============

__global__ __launch_bounds__(256) void k_hist(const int* __restrict__ rowIdx,
                                              int* __restrict__ cnt) {
    int e = blockIdx.x * 256 + threadIdx.x;
    if (e < E_EDGES) atomicAdd(&cnt[rowIdx[e]], 1);
}

__global__ __launch_bounds__(256) void k_bsum(const int* __restrict__ cnt,
                                              int* __restrict__ bsum) {
    __shared__ int lds[256];
    const int tid = threadIdx.x;
    int base = blockIdx.x * SCAN_CHUNK + tid * 16;
    int s = 0;
#pragma unroll
    for (int i = 0; i < 16; ++i) {
        int idx = base + i;
        if (idx < N_NODES) s += cnt[idx];
    }
    lds[tid] = s;
    __syncthreads();
    for (int st = 128; st > 0; st >>= 1) {
        if (tid < st) lds[tid] += lds[tid + st];
        __syncthreads();
    }
    if (tid == 0) bsum[blockIdx.x] = lds[0];
}

__global__ __launch_bounds__(64) void k_bscan(int* __restrict__ bsum,
                                              int* __restrict__ start) {
    if (threadIdx.x == 0) {
        int run = 0;
        for (int i = 0; i < NB_SCAN; ++i) {
            int t = bsum[i];
            bsum[i] = run;
            run += t;
        }
        start[N_NODES] = E_EDGES;
    }
}

__global__ __launch_bounds__(256) void k_starts(const int* __restrict__ cnt,
                                                const int* __restrict__ bsum,
                                                int* __restrict__ start) {
    __shared__ int lds[256];
    const int tid = threadIdx.x;
    int base = blockIdx.x * SCAN_CHUNK + tid * 16;
    int vals[16];
    int s = 0;
#pragma unroll
    for (int i = 0; i < 16; ++i) {
        int idx = base + i;
        int v = (idx < N_NODES) ? cnt[idx] : 0;
        vals[i] = v;
        s += v;
    }
    lds[tid] = s;
    __syncthreads();
    for (int st = 1; st < 256; st <<= 1) {
        int t = (tid >= st) ? lds[tid - st] : 0;
        __syncthreads();
        lds[tid] += t;
        __syncthreads();
    }
    int run = bsum[blockIdx.x] + lds[tid] - s;
#pragma unroll
    for (int i = 0; i < 16; ++i) {
        int idx = base + i;
        if (idx < N_NODES) { start[idx] = run; run += vals[i]; }
    }
}

__global__ __launch_bounds__(256) void k_initcur(const int* __restrict__ start,
                                                 int* __restrict__ cursorA) {
    int b = threadIdx.x;
    cursorA[b] = start[b * ROWS_PER_BUCKET];
}

__global__ __launch_bounds__(256) void k_bucketA(const int* __restrict__ rowIdx,
                                                 const int* __restrict__ colIdx,
                                                 int* __restrict__ cursorA,
                                                 uint2* __restrict__ pairs) {
    __shared__ uint2 stage[EDGES_PER_BLK_A];
    __shared__ unsigned char bmap[EDGES_PER_BLK_A];
    __shared__ int cntL[NBUCK], scanEx[NBUCK], cur[NBUCK], posG[NBUCK];
    const int tid = threadIdx.x;
    const int e0 = blockIdx.x * EDGES_PER_BLK_A;
    const int n = min(EDGES_PER_BLK_A, E_EDGES - e0);

    cntL[tid] = 0;
    __syncthreads();
    for (int i = tid; i < n; i += 256) {
        int b = rowIdx[e0 + i] / ROWS_PER_BUCKET;
        atomicAdd(&cntL[b], 1);
    }
    __syncthreads();
    int myc = cntL[tid];
    scanEx[tid] = myc;
    __syncthreads();
    for (int st = 1; st < 256; st <<= 1) {
        int t = (tid >= st) ? scanEx[tid - st] : 0;
        __syncthreads();
        scanEx[tid] += t;
        __syncthreads();
    }
    int ex = scanEx[tid] - myc;
    __syncthreads();
    scanEx[tid] = ex;
    cur[tid] = ex;
    if (myc) posG[tid] = atomicAdd(&cursorA[tid], myc);
    __syncthreads();
    for (int i = tid; i < n; i += 256) {
        int r = rowIdx[e0 + i];
        int c = colIdx[e0 + i];
        int b = r / ROWS_PER_BUCKET;
        int slot = atomicAdd(&cur[b], 1);
        stage[slot] = make_uint2((unsigned)c, (unsigned)r);
        bmap[slot] = (unsigned char)b;
    }
    __syncthreads();
    for (int i = tid; i < n; i += 256) {
        int b = bmap[i];
        int dst = posG[b] + (i - scanEx[b]);
        pairs[dst] = stage[i];
    }
}

__global__ __launch_bounds__(256) void k_bucketB(const int* __restrict__ start,
                                                 const uint2* __restrict__ pairs,
                                                 int* __restrict__ csr) {
    __shared__ int cur[ROWS_PER_BUCKET];
    const int tid = threadIdx.x;
    const int rowbase = blockIdx.x * ROWS_PER_BUCKET;
    const int nrows = min(ROWS_PER_BUCKET, N_NODES - rowbase);
    for (int i = tid; i < nrows; i += 256) cur[i] = start[rowbase + i];
    __syncthreads();
    const int bBeg = start[rowbase];
    const int bEnd = start[rowbase + nrows];
    for (int i = bBeg + tid; i < bEnd; i += 256) {
        uint2 p = pairs[i];
        int pos = atomicAdd(&cur[(int)p.y - rowbase], 1);
        csr[pos] = (int)p.x;
    }
}

// ============ fused node MLPs ============
// Block = 256 thr = 4 waves. 64 rows/block; row = lane, column-quarter = wave id
// (wave-uniform => weight loads are s_load/SGPR, accumulators stay 16 VGPRs).
// Row activations shared via LDS [64][68] (odd dword stride: conflict-light).

#define SH_STRIDE 68

// o[16] += xrow(LDS, 64 wide) @ w[64][64] column chunk wc (wave-uniform), x scaled
__device__ __forceinline__ void gemm16(const float* xrow,
                                       const float* __restrict__ wc,
                                       float o[16], float scale) {
#pragma unroll 4
    for (int k = 0; k < 64; ++k) {
        float xk = xrow[k] * scale;
        const float* wr = wc + k * 64;
#pragma unroll
        for (int j = 0; j < 16; ++j) o[j] = fmaf(xk, wr[j], o[j]);
    }
}

// stage a contiguous [rows<=64] x 64 f32 block into sh (coalesced)
__device__ __forceinline__ void stage64(const float* __restrict__ src,
                                        float sh[64][SH_STRIDE], int tid, int nrows) {
#pragma unroll
    for (int i = 0; i < 4; ++i) {
        int idx = tid + i * 256;
        int row = idx >> 4;
        int c4 = (idx & 15) * 4;
        float4 v = (row < nrows) ? *(const float4*)(src + (size_t)row * 64 + c4)
                                 : make_float4(0.f, 0.f, 0.f, 0.f);
        *(float4*)(&sh[row][c4]) = v;
    }
}

// stage 64 cols of x (stride 128) into sh
__device__ __forceinline__ void stageX(const float* __restrict__ xbase,
                                       float sh[64][SH_STRIDE], int tid, int nrows) {
#pragma unroll
    for (int i = 0; i < 4; ++i) {
        int idx = tid + i * 256;
        int row = idx >> 4;
        int c4 = (idx & 15) * 4;
        float4 v = (row < nrows) ? *(const float4*)(xbase + (size_t)row * 128 + c4)
                                 : make_float4(0.f, 0.f, 0.f, 0.f);
        *(float4*)(&sh[row][c4]) = v;
    }
}

__device__ __forceinline__ void sh_put16(float sh[64][SH_STRIDE], int lane, int co,
                                         const float o[16]) {
    *(float4*)(&sh[lane][co + 0])  = make_float4(o[0], o[1], o[2], o[3]);
    *(float4*)(&sh[lane][co + 4])  = make_float4(o[4], o[5], o[6], o[7]);
    *(float4*)(&sh[lane][co + 8])  = make_float4(o[8], o[9], o[10], o[11]);
    *(float4*)(&sh[lane][co + 12]) = make_float4(o[12], o[13], o[14], o[15]);
}

__device__ __forceinline__ void g_put16(float* __restrict__ dst, const float o[16]) {
    *(float4*)(dst + 0)  = make_float4(o[0], o[1], o[2], o[3]);
    *(float4*)(dst + 4)  = make_float4(o[4], o[5], o[6], o[7]);
    *(float4*)(dst + 8)  = make_float4(o[8], o[9], o[10], o[11]);
    *(float4*)(dst + 12) = make_float4(o[12], o[13], o[14], o[15]);
}

__device__ __forceinline__ void bf16_put16(ushort_t* __restrict__ dst, const float o[16],
                                           bool relu) {
    float a[16];
#pragma unroll
    for (int j = 0; j < 16; ++j) a[j] = relu ? fmaxf(o[j], 0.0f) : o[j];
    uint4* mv = (uint4*)dst;
    mv[0] = make_uint4(bf16_2(a[0], a[1]), bf16_2(a[2], a[3]),
                       bf16_2(a[4], a[5]), bf16_2(a[6], a[7]));
    mv[1] = make_uint4(bf16_2(a[8], a[9]), bf16_2(a[10], a[11]),
                       bf16_2(a[12], a[13]), bf16_2(a[14], a[15]));
}

// h = x@w_in+b_in ; msg16 = relu(relu(h@m1+b1)@m2+b2)
__global__ __launch_bounds__(256, 4) void k_lin_msg(const float* __restrict__ x,
                                                    const float* __restrict__ w,
                                                    const float* __restrict__ b,
                                                    const float* __restrict__ m1w,
                                                    const float* __restrict__ m1b,
                                                    const float* __restrict__ m2w,
                                                    const float* __restrict__ m2b,
                                                    float* __restrict__ h,
                                                    ushort_t* __restrict__ msg16) {
    __shared__ float sA[64][SH_STRIDE];
    __shared__ float sB[64][SH_STRIDE];
    const int tid = threadIdx.x;
    const int lane = tid & 63;
    const int q = __builtin_amdgcn_readfirstlane(tid >> 6);
    const int co = q * 16;
    const int r0 = blockIdx.x * 64;
    const int r = r0 + lane;
    const bool valid = r < N_NODES;
    const int nrows = min(64, N_NODES - r0);

    float o[16];
#pragma unroll
    for (int j = 0; j < 16; ++j) o[j] = b[co + j];
    // x half 0
    stageX(x + (size_t)r0 * 128, sA, tid, nrows);
    __syncthreads();
    gemm16(sA[lane], w + co, o, 1.0f);
    __syncthreads();
    // x half 1
    stageX(x + (size_t)r0 * 128 + 64, sA, tid, nrows);
    __syncthreads();
    gemm16(sA[lane], w + 64 * 64 + co, o, 1.0f);
    if (valid) g_put16(h + (size_t)r * 64 + co, o);
    sh_put16(sB, lane, co, o);
    __syncthreads();          // sB = h rows ready; sA reads done

    float t[16];
#pragma unroll
    for (int j = 0; j < 16; ++j) t[j] = m1b[co + j];
    gemm16(sB[lane], m1w + co, t, 1.0f);
#pragma unroll
    for (int j = 0; j < 16; ++j) t[j] = fmaxf(t[j], 0.0f);
    sh_put16(sA, lane, co, t);
    __syncthreads();          // sA = relu(m1) ready

#pragma unroll
    for (int j = 0; j < 16; ++j) o[j] = m2b[co + j];
    gemm16(sA[lane], m2w + co, o, 1.0f);
    if (valid) bf16_put16(msg16 + (size_t)r * 64 + co, o, true);
}

// ============ aggregation: gather (wave per node, bf16 msg) ============
__global__ __launch_bounds__(256) void k_gather(const int* __restrict__ start,
                                                const int* __restrict__ csr,
                                                const ushort_t* __restrict__ msg16,
                                                float* __restrict__ agg) {
    const int lane = threadIdx.x & 63;
    const int wid  = threadIdx.x >> 6;
    int r = blockIdx.x * 4 + wid;
    if (r >= N_NODES) return;
    int b = start[r];
    int e0 = start[r + 1];
    float acc0 = 0.0f, acc1 = 0.0f;
    for (int base = b; base < e0; base += 64) {
        int n = e0 - base;
        if (n > 64) n = 64;
        int c = 0;
        if (base + lane < e0) c = csr[base + lane];
        int j = 0;
        for (; j + 4 <= n; j += 4) {
            int c0 = __shfl(c, j, 64);
            int c1 = __shfl(c, j + 1, 64);
            int c2 = __shfl(c, j + 2, 64);
            int c3 = __shfl(c, j + 3, 64);
            float l0 = bf16_f(msg16[(size_t)c0 * 64 + lane]);
            float l1 = bf16_f(msg16[(size_t)c1 * 64 + lane]);
            float l2 = bf16_f(msg16[(size_t)c2 * 64 + lane]);
            float l3 = bf16_f(msg16[(size_t)c3 * 64 + lane]);
            acc0 += l0 + l2;
            acc1 += l1 + l3;
        }
        for (; j < n; ++j) {
            int cj = __shfl(c, j, 64);
            acc0 += bf16_f(msg16[(size_t)cj * 64 + lane]);
        }
    }
    agg[(size_t)r * 64 + lane] = acc0 + acc1;
}

// ---- update layer0 then msg layer1, fused ----
__global__ __launch_bounds__(256, 4) void k_update_msg(float* __restrict__ h,
                                                       const float* __restrict__ agg,
                                                       const int* __restrict__ cnt,
                                                       const float* __restrict__ u1,
                                                       const float* __restrict__ b1,
                                                       const float* __restrict__ u2,
                                                       const float* __restrict__ b2,
                                                       const float* __restrict__ m1w,
                                                       const float* __restrict__ m1b,
                                                       const float* __restrict__ m2w,
                                                       const float* __restrict__ m2b,
                                                       ushort_t* __restrict__ msg16) {
    __shared__ float sA[64][SH_STRIDE];   // h rows, later h_new rows
    __shared__ float sB[64][SH_STRIDE];   // agg rows, later intermediates
    const int tid = threadIdx.x;
    const int lane = tid & 63;
    const int q = __builtin_amdgcn_readfirstlane(tid >> 6);
    const int co = q * 16;
    const int r0 = blockIdx.x * 64;
    const int r = r0 + lane;
    const bool valid = r < N_NODES;
    const int nrows = min(64, N_NODES - r0);

    stage64(h + (size_t)r0 * 64, sA, tid, nrows);
    stage64(agg + (size_t)r0 * 64, sB, tid, nrows);
    float inv = valid ? (1.0f / fmaxf((float)cnt[r], 1.0f)) : 0.0f;
    __syncthreads();

    // u1 (K=128): h part + agg/deg part
    float t[16];
#pragma unroll
    for (int j = 0; j < 16; ++j) t[j] = b1[co + j];
    gemm16(sA[lane], u1 + co, t, 1.0f);
    gemm16(sB[lane], u1 + 64 * 64 + co, t, inv);
#pragma unroll
    for (int j = 0; j < 16; ++j) t[j] = fmaxf(t[j], 0.0f);
    __syncthreads();          // agg reads done -> sB reusable
    sh_put16(sB, lane, co, t);
    __syncthreads();

    // u2 + residual
    float o[16];
#pragma unroll
    for (int j = 0; j < 16; ++j) o[j] = b2[co + j];
    gemm16(sB[lane], u2 + co, o, 1.0f);
#pragma unroll
    for (int j = 0; j < 16; ++j) o[j] += sA[lane][co + j];
    if (valid) g_put16(h + (size_t)r * 64 + co, o);
    __syncthreads();          // h reads done -> sA reusable
    sh_put16(sA, lane, co, o);
    __syncthreads();

    // m1
#pragma unroll
    for (int j = 0; j < 16; ++j) t[j] = m1b[co + j];
    gemm16(sA[lane], m1w + co, t, 1.0f);
#pragma unroll
    for (int j = 0; j < 16; ++j) t[j] = fmaxf(t[j], 0.0f);
    sh_put16(sB, lane, co, t);
    __syncthreads();

    // m2
#pragma unroll
    for (int j = 0; j < 16; ++j) o[j] = m2b[co + j];
    gemm16(sB[lane], m2w + co, o, 1.0f);
    if (valid) bf16_put16(msg16 + (size_t)r * 64 + co, o, true);
}

// ---- update layer1 then head precompute, fused (h_new never hits memory) ----
__global__ __launch_bounds__(256, 4) void k_update_headpre(const float* __restrict__ h,
                                                           const float* __restrict__ agg,
                                                           const int* __restrict__ cnt,
                                                           const float* __restrict__ u1,
                                                           const float* __restrict__ b1,
                                                           const float* __restrict__ u2,
                                                           const float* __restrict__ b2,
                                                           const float* __restrict__ hw1,
                                                           const float* __restrict__ hb1,
                                                           ushort_t* __restrict__ hA16,
                                                           ushort_t* __restrict__ hB16) {
    __shared__ float sA[64][SH_STRIDE];
    __shared__ float sB[64][SH_STRIDE];
    const int tid = threadIdx.x;
    const int lane = tid & 63;
    const int q = __builtin_amdgcn_readfirstlane(tid >> 6);
    const int co = q * 16;
    const int r0 = blockIdx.x * 64;
    const int r = r0 + lane;
    const bool valid = r < N_NODES;
    const int nrows = min(64, N_NODES - r0);

    stage64(h + (size_t)r0 * 64, sA, tid, nrows);
    stage64(agg + (size_t)r0 * 64, sB, tid, nrows);
    float dv = valid ? (float)cnt[r] : 0.0f;
    float inv = 1.0f / fmaxf(dv, 1.0f);
    __syncthreads();

    float t[16];
#pragma unroll
    for (int j = 0; j < 16; ++j) t[j] = b1[co + j];
    gemm16(sA[lane], u1 + co, t, 1.0f);
    gemm16(sB[lane], u1 + 64 * 64 + co, t, inv);
#pragma unroll
    for (int j = 0; j < 16; ++j) t[j] = fmaxf(t[j], 0.0f);
    __syncthreads();
    sh_put16(sB, lane, co, t);
    __syncthreads();

    float o[16];
#pragma unroll
    for (int j = 0; j < 16; ++j) o[j] = b2[co + j];
    gemm16(sB[lane], u2 + co, o, 1.0f);
#pragma unroll
    for (int j = 0; j < 16; ++j) o[j] += sA[lane][co + j];
    __syncthreads();
    sh_put16(sA, lane, co, o);   // sA = h_new rows
    __syncthreads();

    // headpre A
#pragma unroll
    for (int j = 0; j < 16; ++j) t[j] = hb1[co + j] + dv * hw1[128 * 64 + co + j];
    gemm16(sA[lane], hw1 + co, t, 1.0f);
    if (valid) bf16_put16(hA16 + (size_t)r * 64 + co, t, false);

    // headpre B
#pragma unroll
    for (int j = 0; j < 16; ++j) t[j] = dv * hw1[129 * 64 + co + j];
    gemm16(sA[lane], hw1 + 64 * 64 + co, t, 1.0f);
    if (valid) bf16_put16(hB16 + (size_t)r * 64 + co, t, false);
}

// ------- out[e] = out[e+HALF] = softplus(relu(hA[src]+hB[dst]) . h2w + h2b) + 1e-6 ------
__global__ __launch_bounds__(256) void k_head(const int* __restrict__ rowIdx,
                                              const int* __restrict__ colIdx,
                                              const ushort_t* __restrict__ hA16,
                                              const ushort_t* __restrict__ hB16,
                                              const float* __restrict__ w2,
                                              const float* __restrict__ b2,
                                              float* __restrict__ out) {
    const int lane = threadIdx.x & 63;
    const int sub = lane & 15;
    const int grp = lane >> 4;
    const int waveId = (blockIdx.x * 256 + threadIdx.x) >> 6;
    const int step = gridDim.x * 4 * 4;
    const float4 wv = *(const float4*)(w2 + sub * 4);
    const float b2v = b2[0];
    for (int e = waveId * 4 + grp; e < HALF_E; e += step) {
        int s = rowIdx[e];
        int d = colIdx[e];
        ushort4 a4 = *(const ushort4*)(hA16 + (size_t)s * 64 + sub * 4);
        ushort4 b4 = *(const ushort4*)(hB16 + (size_t)d * 64 + sub * 4);
        float t0 = fmaxf(bf16_f(a4.x) + bf16_f(b4.x), 0.0f);
        float t1 = fmaxf(bf16_f(a4.y) + bf16_f(b4.y), 0.0f);
        float t2 = fmaxf(bf16_f(a4.z) + bf16_f(b4.z), 0.0f);
        float t3 = fmaxf(bf16_f(a4.w) + bf16_f(b4.w), 0.0f);
        float p = t0 * wv.x + t1 * wv.y + t2 * wv.z + t3 * wv.w;
        p += __shfl_xor(p, 1);
        p += __shfl_xor(p, 2);
        p += __shfl_xor(p, 4);
        p += __shfl_xor(p, 8);
        if (sub == 0) {
            float sv = p + b2v;
            float sp = fmaxf(sv, 0.0f) + log1pf(expf(-fabsf(sv)));
            float wvv = sp + 1e-6f;
            out[e] = wvv;
            out[e + HALF_E] = wvv;
        }
    }
}

extern "C" void kernel_launch(void* const* d_in, const int* in_sizes, int n_in,
                              void* d_out, int out_size, void* d_ws, size_t ws_size,
                              hipStream_t stream) {
    const float* x      = (const float*)d_in[0];
    const int*   rowIdx = (const int*)d_in[1];
    const int*   colIdx = rowIdx + E_EDGES;
    const float* w_in   = (const float*)d_in[2];
    const float* b_in   = (const float*)d_in[3];
    const float* l0_m1w = (const float*)d_in[4];
    const float* l0_m1b = (const float*)d_in[5];
    const float* l0_m2w = (const float*)d_in[6];
    const float* l0_m2b = (const float*)d_in[7];
    const float* l0_u1w = (const float*)d_in[8];
    const float* l0_u1b = (const float*)d_in[9];
    const float* l0_u2w = (const float*)d_in[10];
    const float* l0_u2b = (const float*)d_in[11];
    const float* l1_m1w = (const float*)d_in[12];
    const float* l1_m1b = (const float*)d_in[13];
    const float* l1_m2w = (const float*)d_in[14];
    const float* l1_m2b = (const float*)d_in[15];
    const float* l1_u1w = (const float*)d_in[16];
    const float* l1_u1b = (const float*)d_in[17];
    const float* l1_u2w = (const float*)d_in[18];
    const float* l1_u2b = (const float*)d_in[19];
    const float* h1w    = (const float*)d_in[20];
    const float* h1b    = (const float*)d_in[21];
    const float* h2w    = (const float*)d_in[22];
    const float* h2b    = (const float*)d_in[23];

    float* out = (float*)d_out;

    float*    h     = (float*)d_ws;                         // N x 64 f32
    float*    agg   = h + (size_t)N_NODES * 64;             // N x 64 f32
    ushort_t* msg16 = (ushort_t*)(agg + (size_t)N_NODES * 64); // N x 64 bf16
    ushort_t* hB16  = msg16 + (size_t)N_NODES * 64;         // N x 64 bf16
    int*      cnt   = (int*)(hB16 + (size_t)N_NODES * 64);  // N
    int*      start = cnt + N_NODES;                        // N + 1
    int*      bsum  = start + N_NODES + 1;                  // NB_SCAN (pad 32)
    int*      curA  = bsum + 32;                            // NBUCK
    int*      csr   = curA + NBUCK;                         // E
    uint2*    pairs = (uint2*)agg;                          // alias: dead before gather writes agg
    ushort_t* hA16  = msg16;                                // alias: msg16 dead after gather1

    const int nb64 = (N_NODES + 63) / 64;                   // 1563 blocks for MLP kernels
    const int edgeBlocks = (E_EDGES + 255) / 256;
    const int gatherBlocks = (N_NODES + 3) / 4;

    // ---- CSR build (bucket sort: coalesced writes) ----
    hipMemsetAsync(cnt, 0, (size_t)N_NODES * sizeof(int), stream);
    k_hist<<<edgeBlocks, 256, 0, stream>>>(rowIdx, cnt);
    k_bsum<<<NB_SCAN, 256, 0, stream>>>(cnt, bsum);
    k_bscan<<<1, 64, 0, stream>>>(bsum, start);
    k_starts<<<NB_SCAN, 256, 0, stream>>>(cnt, bsum, start);
    k_initcur<<<1, NBUCK, 0, stream>>>(start, curA);
    k_bucketA<<<NBLK_A, 256, 0, stream>>>(rowIdx, colIdx, curA, pairs);
    k_bucketB<<<NBUCK, 256, 0, stream>>>(start, pairs, csr);

    // ---- input linear + layer0 message (fused) ----
    k_lin_msg<<<nb64, 256, 0, stream>>>(x, w_in, b_in,
                                        l0_m1w, l0_m1b, l0_m2w, l0_m2b, h, msg16);
    // ---- layer 0 aggregate; update + layer1 message (fused) ----
    k_gather<<<gatherBlocks, 256, 0, stream>>>(start, csr, msg16, agg);
    k_update_msg<<<nb64, 256, 0, stream>>>(h, agg, cnt,
                                           l0_u1w, l0_u1b, l0_u2w, l0_u2b,
                                           l1_m1w, l1_m1b, l1_m2w, l1_m2b, msg16);
    // ---- layer 1 aggregate; update + head precompute (fused) ----
    k_gather<<<gatherBlocks, 256, 0, stream>>>(start, csr, msg16, agg);
    k_update_headpre<<<nb64, 256, 0, stream>>>(h, agg, cnt,
                                               l1_u1w, l1_u1b, l1_u2w, l1_u2b,
                                               h1w, h1b, hA16, hB16);
    // ---- head ----
    k_head<<<4096, 256, 0, stream>>>(rowIdx, colIdx, hA16, hB16, h2w, h2b, out);
}

// Round 9
// 431.771 us; speedup vs baseline: 6.3293x; 1.0537x over previous
//
#include <hip/hip_runtime.h>
#include <math.h>

#define N_NODES 100000
#define E_EDGES 1600000
#define HALF_E  (E_EDGES / 2)

#define NBUCK 256
#define ROWS_PER_BUCKET ((N_NODES + NBUCK - 1) / NBUCK)   // 391
#define EDGES_PER_BLK_A 4096
#define NBLK_A ((E_EDGES + EDGES_PER_BLK_A - 1) / EDGES_PER_BLK_A)  // 391

typedef unsigned short ushort_t;

// ---- bf16 helpers (RNE pack, cheap unpack) ----
__device__ __forceinline__ unsigned bf16_1(float f) {
    unsigned u = __float_as_uint(f);
    return (u + 0x7fffu + ((u >> 16) & 1u)) >> 16;
}
__device__ __forceinline__ unsigned bf16_2(float a, float b) {
    return bf16_1(a) | (bf16_1(b) << 16);
}
__device__ __forceinline__ float bf16_f(ushort_t us) {
    return __uint_as_float(((unsigned)us) << 16);
}

// ============ CSR build (bucketed, no full-N histogram passes) ============

// 256-bucket histogram of rows
__global__ __launch_bounds__(256) void k_bhist(const int* __restrict__ rowIdx,
                                               int* __restrict__ bcnt) {
    __shared__ int c[NBUCK];
    const int tid = threadIdx.x;
    c[tid] = 0;
    __syncthreads();
    for (int e = blockIdx.x * 256 + tid; e < E_EDGES; e += gridDim.x * 256)
        atomicAdd(&c[rowIdx[e] / ROWS_PER_BUCKET], 1);
    __syncthreads();
    if (c[tid]) atomicAdd(&bcnt[tid], c[tid]);
}

// exclusive scan of 256 bucket counts -> bbase[257]; also seeds curA, start[N]
__global__ __launch_bounds__(256) void k_bscan256(const int* __restrict__ bcnt,
                                                  int* __restrict__ bbase,
                                                  int* __restrict__ curA,
                                                  int* __restrict__ start) {
    __shared__ int sc[NBUCK];
    const int tid = threadIdx.x;
    int v = bcnt[tid];
    sc[tid] = v;
    __syncthreads();
    for (int st = 1; st < 256; st <<= 1) {
        int t = (tid >= st) ? sc[tid - st] : 0;
        __syncthreads();
        sc[tid] += t;
        __syncthreads();
    }
    int excl = sc[tid] - v;
    bbase[tid] = excl;
    curA[tid] = excl;
    if (tid == 255) bbase[256] = sc[255];
    if (tid == 0) start[N_NODES] = E_EDGES;
}

// Pass A: bucket edges into pairs[] (grouped by 391-row buckets), coalesced runs.
__global__ __launch_bounds__(256) void k_bucketA(const int* __restrict__ rowIdx,
                                                 const int* __restrict__ colIdx,
                                                 int* __restrict__ cursorA,
                                                 uint2* __restrict__ pairs) {
    __shared__ uint2 stage[EDGES_PER_BLK_A];
    __shared__ unsigned char bmap[EDGES_PER_BLK_A];
    __shared__ int cntL[NBUCK], scanEx[NBUCK], cur[NBUCK], posG[NBUCK];
    const int tid = threadIdx.x;
    const int e0 = blockIdx.x * EDGES_PER_BLK_A;
    const int n = min(EDGES_PER_BLK_A, E_EDGES - e0);

    cntL[tid] = 0;
    __syncthreads();
    for (int i = tid; i < n; i += 256) {
        int b = rowIdx[e0 + i] / ROWS_PER_BUCKET;
        atomicAdd(&cntL[b], 1);
    }
    __syncthreads();
    int myc = cntL[tid];
    scanEx[tid] = myc;
    __syncthreads();
    for (int st = 1; st < 256; st <<= 1) {
        int t = (tid >= st) ? scanEx[tid - st] : 0;
        __syncthreads();
        scanEx[tid] += t;
        __syncthreads();
    }
    int ex = scanEx[tid] - myc;
    __syncthreads();
    scanEx[tid] = ex;
    cur[tid] = ex;
    if (myc) posG[tid] = atomicAdd(&cursorA[tid], myc);
    __syncthreads();
    for (int i = tid; i < n; i += 256) {
        int r = rowIdx[e0 + i];
        int c = colIdx[e0 + i];
        int b = r / ROWS_PER_BUCKET;
        int slot = atomicAdd(&cur[b], 1);
        stage[slot] = make_uint2((unsigned)c, (unsigned)r);
        bmap[slot] = (unsigned char)b;
    }
    __syncthreads();
    for (int i = tid; i < n; i += 256) {
        int b = bmap[i];
        int dst = posG[b] + (i - scanEx[b]);
        pairs[dst] = stage[i];
    }
}

// Pass B: per bucket: row histogram + scan (writes start[]), then scatter csr.
__global__ __launch_bounds__(256) void k_bucketB(const int* __restrict__ bbase,
                                                 const uint2* __restrict__ pairs,
                                                 int* __restrict__ start,
                                                 int* __restrict__ csr) {
    __shared__ int cur[ROWS_PER_BUCKET];
    __shared__ int scn[512];
    const int tid = threadIdx.x;
    const int rowbase = blockIdx.x * ROWS_PER_BUCKET;
    const int nrows = min(ROWS_PER_BUCKET, N_NODES - rowbase);
    for (int i = tid; i < nrows; i += 256) cur[i] = 0;
    __syncthreads();
    const int bBeg = bbase[blockIdx.x];
    const int bEnd = bbase[blockIdx.x + 1];
    for (int i = bBeg + tid; i < bEnd; i += 256)
        atomicAdd(&cur[(int)pairs[i].y - rowbase], 1);
    __syncthreads();
    // inclusive scan over 512-padded row counts
    scn[tid] = (tid < nrows) ? cur[tid] : 0;
    scn[tid + 256] = (tid + 256 < nrows) ? cur[tid + 256] : 0;
    __syncthreads();
    for (int st = 1; st < 512; st <<= 1) {
        int i0 = tid, i1 = tid + 256;
        int t0 = (i0 >= st) ? scn[i0 - st] : 0;
        int t1 = (i1 >= st) ? scn[i1 - st] : 0;
        __syncthreads();
        scn[i0] += t0;
        scn[i1] += t1;
        __syncthreads();
    }
    for (int i = tid; i < nrows; i += 256) {
        int sv = bBeg + scn[i] - cur[i];   // exclusive + bucket base
        start[rowbase + i] = sv;
        cur[i] = sv;
    }
    __syncthreads();
    for (int i = bBeg + tid; i < bEnd; i += 256) {
        uint2 p = pairs[i];
        int pos = atomicAdd(&cur[(int)p.y - rowbase], 1);
        csr[pos] = (int)p.x;
    }
}

// ============ fused node MLPs ============
// Block = 256 thr = 4 waves; 64 rows/block; row = lane, column-quarter = wave id
// (wave-uniform weight columns => s_load/SGPR weights). ONE f32 LDS buffer
// [64][68] (17.4 KB) -> ~8 blocks/CU; phases serialized with barriers.

#define SH_STRIDE 68

__device__ __forceinline__ void gemm16(const float* xrow,
                                       const float* __restrict__ wc,
                                       float o[16], float scale) {
#pragma unroll 4
    for (int k = 0; k < 64; ++k) {
        float xk = xrow[k] * scale;
        const float* wr = wc + k * 64;
#pragma unroll
        for (int j = 0; j < 16; ++j) o[j] = fmaf(xk, wr[j], o[j]);
    }
}

// stage a contiguous [rows<=64] x 64 f32 block into S (coalesced)
__device__ __forceinline__ void stage64(const float* __restrict__ src,
                                        float S[64][SH_STRIDE], int tid, int nrows) {
#pragma unroll
    for (int i = 0; i < 4; ++i) {
        int idx = tid + i * 256;
        int row = idx >> 4;
        int c4 = (idx & 15) * 4;
        float4 v = (row < nrows) ? *(const float4*)(src + (size_t)row * 64 + c4)
                                 : make_float4(0.f, 0.f, 0.f, 0.f);
        *(float4*)(&S[row][c4]) = v;
    }
}

// stage 64 cols of x (row stride 128) into S
__device__ __forceinline__ void stageX(const float* __restrict__ xbase,
                                       float S[64][SH_STRIDE], int tid, int nrows) {
#pragma unroll
    for (int i = 0; i < 4; ++i) {
        int idx = tid + i * 256;
        int row = idx >> 4;
        int c4 = (idx & 15) * 4;
        float4 v = (row < nrows) ? *(const float4*)(xbase + (size_t)row * 128 + c4)
                                 : make_float4(0.f, 0.f, 0.f, 0.f);
        *(float4*)(&S[row][c4]) = v;
    }
}

__device__ __forceinline__ void sh_put16(float S[64][SH_STRIDE], int lane, int co,
                                         const float o[16]) {
    *(float4*)(&S[lane][co + 0])  = make_float4(o[0], o[1], o[2], o[3]);
    *(float4*)(&S[lane][co + 4])  = make_float4(o[4], o[5], o[6], o[7]);
    *(float4*)(&S[lane][co + 8])  = make_float4(o[8], o[9], o[10], o[11]);
    *(float4*)(&S[lane][co + 12]) = make_float4(o[12], o[13], o[14], o[15]);
}

__device__ __forceinline__ void g_put16(float* __restrict__ dst, const float o[16]) {
    *(float4*)(dst + 0)  = make_float4(o[0], o[1], o[2], o[3]);
    *(float4*)(dst + 4)  = make_float4(o[4], o[5], o[6], o[7]);
    *(float4*)(dst + 8)  = make_float4(o[8], o[9], o[10], o[11]);
    *(float4*)(dst + 12) = make_float4(o[12], o[13], o[14], o[15]);
}

__device__ __forceinline__ void bf16_put16(ushort_t* __restrict__ dst, const float o[16],
                                           bool relu) {
    float a[16];
#pragma unroll
    for (int j = 0; j < 16; ++j) a[j] = relu ? fmaxf(o[j], 0.0f) : o[j];
    uint4* mv = (uint4*)dst;
    mv[0] = make_uint4(bf16_2(a[0], a[1]), bf16_2(a[2], a[3]),
                       bf16_2(a[4], a[5]), bf16_2(a[6], a[7]));
    mv[1] = make_uint4(bf16_2(a[8], a[9]), bf16_2(a[10], a[11]),
                       bf16_2(a[12], a[13]), bf16_2(a[14], a[15]));
}

// h = x@w_in+b_in ; msg16 = relu(relu(h@m1+b1)@m2+b2)
__global__ __launch_bounds__(256, 4) void k_lin_msg(const float* __restrict__ x,
                                                    const float* __restrict__ w,
                                                    const float* __restrict__ b,
                                                    const float* __restrict__ m1w,
                                                    const float* __restrict__ m1b,
                                                    const float* __restrict__ m2w,
                                                    const float* __restrict__ m2b,
                                                    float* __restrict__ h,
                                                    ushort_t* __restrict__ msg16) {
    __shared__ float S[64][SH_STRIDE];
    const int tid = threadIdx.x;
    const int lane = tid & 63;
    const int q = __builtin_amdgcn_readfirstlane(tid >> 6);
    const int co = q * 16;
    const int r0 = blockIdx.x * 64;
    const int r = r0 + lane;
    const bool valid = r < N_NODES;
    const int nrows = min(64, N_NODES - r0);

    float o[16];
#pragma unroll
    for (int j = 0; j < 16; ++j) o[j] = b[co + j];
    stageX(x + (size_t)r0 * 128, S, tid, nrows);
    __syncthreads();
    gemm16(S[lane], w + co, o, 1.0f);
    __syncthreads();
    stageX(x + (size_t)r0 * 128 + 64, S, tid, nrows);
    __syncthreads();
    gemm16(S[lane], w + 64 * 64 + co, o, 1.0f);
    if (valid) g_put16(h + (size_t)r * 64 + co, o);
    __syncthreads();
    sh_put16(S, lane, co, o);
    __syncthreads();

    float t[16];
#pragma unroll
    for (int j = 0; j < 16; ++j) t[j] = m1b[co + j];
    gemm16(S[lane], m1w + co, t, 1.0f);
#pragma unroll
    for (int j = 0; j < 16; ++j) t[j] = fmaxf(t[j], 0.0f);
    __syncthreads();
    sh_put16(S, lane, co, t);
    __syncthreads();

#pragma unroll
    for (int j = 0; j < 16; ++j) o[j] = m2b[co + j];
    gemm16(S[lane], m2w + co, o, 1.0f);
    if (valid) bf16_put16(msg16 + (size_t)r * 64 + co, o, true);
}

// ============ aggregation: gather (wave per node, bf16 msg) ============
__global__ __launch_bounds__(256) void k_gather(const int* __restrict__ start,
                                                const int* __restrict__ csr,
                                                const ushort_t* __restrict__ msg16,
                                                float* __restrict__ agg) {
    const int lane = threadIdx.x & 63;
    const int wid  = threadIdx.x >> 6;
    int r = blockIdx.x * 4 + wid;
    if (r >= N_NODES) return;
    int b = start[r];
    int e0 = start[r + 1];
    float acc0 = 0.0f, acc1 = 0.0f;
    for (int base = b; base < e0; base += 64) {
        int n = e0 - base;
        if (n > 64) n = 64;
        int c = 0;
        if (base + lane < e0) c = csr[base + lane];
        int j = 0;
        for (; j + 4 <= n; j += 4) {
            int c0 = __shfl(c, j, 64);
            int c1 = __shfl(c, j + 1, 64);
            int c2 = __shfl(c, j + 2, 64);
            int c3 = __shfl(c, j + 3, 64);
            float l0 = bf16_f(msg16[(size_t)c0 * 64 + lane]);
            float l1 = bf16_f(msg16[(size_t)c1 * 64 + lane]);
            float l2 = bf16_f(msg16[(size_t)c2 * 64 + lane]);
            float l3 = bf16_f(msg16[(size_t)c3 * 64 + lane]);
            acc0 += l0 + l2;
            acc1 += l1 + l3;
        }
        for (; j < n; ++j) {
            int cj = __shfl(c, j, 64);
            acc0 += bf16_f(msg16[(size_t)cj * 64 + lane]);
        }
    }
    agg[(size_t)r * 64 + lane] = acc0 + acc1;
}

// ---- update layer0 then msg layer1, fused (single LDS buffer) ----
__global__ __launch_bounds__(256, 4) void k_update_msg(float* __restrict__ h,
                                                       const float* __restrict__ agg,
                                                       const int* __restrict__ start,
                                                       const float* __restrict__ u1,
                                                       const float* __restrict__ b1,
                                                       const float* __restrict__ u2,
                                                       const float* __restrict__ b2,
                                                       const float* __restrict__ m1w,
                                                       const float* __restrict__ m1b,
                                                       const float* __restrict__ m2w,
                                                       const float* __restrict__ m2b,
                                                       ushort_t* __restrict__ msg16) {
    __shared__ float S[64][SH_STRIDE];
    const int tid = threadIdx.x;
    const int lane = tid & 63;
    const int q = __builtin_amdgcn_readfirstlane(tid >> 6);
    const int co = q * 16;
    const int r0 = blockIdx.x * 64;
    const int r = r0 + lane;
    const bool valid = r < N_NODES;
    const int nrows = min(64, N_NODES - r0);

    float inv = 0.0f;
    if (valid) {
        float dv = (float)(start[r + 1] - start[r]);
        inv = 1.0f / fmaxf(dv, 1.0f);
    }

    // u1 agg-part
    float t[16];
#pragma unroll
    for (int j = 0; j < 16; ++j) t[j] = b1[co + j];
    stage64(agg + (size_t)r0 * 64, S, tid, nrows);
    __syncthreads();
    gemm16(S[lane], u1 + 64 * 64 + co, t, inv);
    __syncthreads();
    // u1 h-part (+ grab residual while S holds h)
    stage64(h + (size_t)r0 * 64, S, tid, nrows);
    __syncthreads();
    gemm16(S[lane], u1 + co, t, 1.0f);
    float res[16];
#pragma unroll
    for (int j = 0; j < 16; ++j) {
        res[j] = S[lane][co + j];
        t[j] = fmaxf(t[j], 0.0f);
    }
    __syncthreads();
    sh_put16(S, lane, co, t);
    __syncthreads();

    // u2 + residual -> h_new
    float o[16];
#pragma unroll
    for (int j = 0; j < 16; ++j) o[j] = b2[co + j];
    gemm16(S[lane], u2 + co, o, 1.0f);
#pragma unroll
    for (int j = 0; j < 16; ++j) o[j] += res[j];
    if (valid) g_put16(h + (size_t)r * 64 + co, o);
    __syncthreads();
    sh_put16(S, lane, co, o);
    __syncthreads();

    // m1
#pragma unroll
    for (int j = 0; j < 16; ++j) t[j] = m1b[co + j];
    gemm16(S[lane], m1w + co, t, 1.0f);
#pragma unroll
    for (int j = 0; j < 16; ++j) t[j] = fmaxf(t[j], 0.0f);
    __syncthreads();
    sh_put16(S, lane, co, t);
    __syncthreads();

    // m2
#pragma unroll
    for (int j = 0; j < 16; ++j) o[j] = m2b[co + j];
    gemm16(S[lane], m2w + co, o, 1.0f);
    if (valid) bf16_put16(msg16 + (size_t)r * 64 + co, o, true);
}

// ---- update layer1 then head precompute, fused (single LDS buffer) ----
__global__ __launch_bounds__(256, 4) void k_update_headpre(const float* __restrict__ h,
                                                           const float* __restrict__ agg,
                                                           const int* __restrict__ start,
                                                           const float* __restrict__ u1,
                                                           const float* __restrict__ b1,
                                                           const float* __restrict__ u2,
                                                           const float* __restrict__ b2,
                                                           const float* __restrict__ hw1,
                                                           const float* __restrict__ hb1,
                                                           ushort_t* __restrict__ hA16,
                                                           ushort_t* __restrict__ hB16) {
    __shared__ float S[64][SH_STRIDE];
    const int tid = threadIdx.x;
    const int lane = tid & 63;
    const int q = __builtin_amdgcn_readfirstlane(tid >> 6);
    const int co = q * 16;
    const int r0 = blockIdx.x * 64;
    const int r = r0 + lane;
    const bool valid = r < N_NODES;
    const int nrows = min(64, N_NODES - r0);

    float dv = 0.0f;
    if (valid) dv = (float)(start[r + 1] - start[r]);
    float inv = 1.0f / fmaxf(dv, 1.0f);

    float t[16];
#pragma unroll
    for (int j = 0; j < 16; ++j) t[j] = b1[co + j];
    stage64(agg + (size_t)r0 * 64, S, tid, nrows);
    __syncthreads();
    gemm16(S[lane], u1 + 64 * 64 + co, t, inv);
    __syncthreads();
    stage64(h + (size_t)r0 * 64, S, tid, nrows);
    __syncthreads();
    gemm16(S[lane], u1 + co, t, 1.0f);
    float res[16];
#pragma unroll
    for (int j = 0; j < 16; ++j) {
        res[j] = S[lane][co + j];
        t[j] = fmaxf(t[j], 0.0f);
    }
    __syncthreads();
    sh_put16(S, lane, co, t);
    __syncthreads();

    float o[16];
#pragma unroll
    for (int j = 0; j < 16; ++j) o[j] = b2[co + j];
    gemm16(S[lane], u2 + co, o, 1.0f);
#pragma unroll
    for (int j = 0; j < 16; ++j) o[j] += res[j];
    __syncthreads();
    sh_put16(S, lane, co, o);     // S = h_new rows
    __syncthreads();

    // headpre A
#pragma unroll
    for (int j = 0; j < 16; ++j) t[j] = hb1[co + j] + dv * hw1[128 * 64 + co + j];
    gemm16(S[lane], hw1 + co, t, 1.0f);
    if (valid) bf16_put16(hA16 + (size_t)r * 64 + co, t, false);

    // headpre B (same S, no barrier needed)
#pragma unroll
    for (int j = 0; j < 16; ++j) t[j] = dv * hw1[129 * 64 + co + j];
    gemm16(S[lane], hw1 + 64 * 64 + co, t, 1.0f);
    if (valid) bf16_put16(hB16 + (size_t)r * 64 + co, t, false);
}

// ------- out[e] = out[e+HALF] = softplus(relu(hA[src]+hB[dst]) . h2w + h2b) + 1e-6 ------
__global__ __launch_bounds__(256) void k_head(const int* __restrict__ rowIdx,
                                              const int* __restrict__ colIdx,
                                              const ushort_t* __restrict__ hA16,
                                              const ushort_t* __restrict__ hB16,
                                              const float* __restrict__ w2,
                                              const float* __restrict__ b2,
                                              float* __restrict__ out) {
    const int lane = threadIdx.x & 63;
    const int sub = lane & 15;
    const int grp = lane >> 4;
    const int waveId = (blockIdx.x * 256 + threadIdx.x) >> 6;
    const int step = gridDim.x * 4 * 4;
    const float4 wv = *(const float4*)(w2 + sub * 4);
    const float b2v = b2[0];
    for (int e = waveId * 4 + grp; e < HALF_E; e += step) {
        int s = rowIdx[e];
        int d = colIdx[e];
        ushort4 a4 = *(const ushort4*)(hA16 + (size_t)s * 64 + sub * 4);
        ushort4 b4 = *(const ushort4*)(hB16 + (size_t)d * 64 + sub * 4);
        float t0 = fmaxf(bf16_f(a4.x) + bf16_f(b4.x), 0.0f);
        float t1 = fmaxf(bf16_f(a4.y) + bf16_f(b4.y), 0.0f);
        float t2 = fmaxf(bf16_f(a4.z) + bf16_f(b4.z), 0.0f);
        float t3 = fmaxf(bf16_f(a4.w) + bf16_f(b4.w), 0.0f);
        float p = t0 * wv.x + t1 * wv.y + t2 * wv.z + t3 * wv.w;
        p += __shfl_xor(p, 1);
        p += __shfl_xor(p, 2);
        p += __shfl_xor(p, 4);
        p += __shfl_xor(p, 8);
        if (sub == 0) {
            float sv = p + b2v;
            float sp = fmaxf(sv, 0.0f) + log1pf(expf(-fabsf(sv)));
            float wvv = sp + 1e-6f;
            out[e] = wvv;
            out[e + HALF_E] = wvv;
        }
    }
}

extern "C" void kernel_launch(void* const* d_in, const int* in_sizes, int n_in,
                              void* d_out, int out_size, void* d_ws, size_t ws_size,
                              hipStream_t stream) {
    const float* x      = (const float*)d_in[0];
    const int*   rowIdx = (const int*)d_in[1];
    const int*   colIdx = rowIdx + E_EDGES;
    const float* w_in   = (const float*)d_in[2];
    const float* b_in   = (const float*)d_in[3];
    const float* l0_m1w = (const float*)d_in[4];
    const float* l0_m1b = (const float*)d_in[5];
    const float* l0_m2w = (const float*)d_in[6];
    const float* l0_m2b = (const float*)d_in[7];
    const float* l0_u1w = (const float*)d_in[8];
    const float* l0_u1b = (const float*)d_in[9];
    const float* l0_u2w = (const float*)d_in[10];
    const float* l0_u2b = (const float*)d_in[11];
    const float* l1_m1w = (const float*)d_in[12];
    const float* l1_m1b = (const float*)d_in[13];
    const float* l1_m2w = (const float*)d_in[14];
    const float* l1_m2b = (const float*)d_in[15];
    const float* l1_u1w = (const float*)d_in[16];
    const float* l1_u1b = (const float*)d_in[17];
    const float* l1_u2w = (const float*)d_in[18];
    const float* l1_u2b = (const float*)d_in[19];
    const float* h1w    = (const float*)d_in[20];
    const float* h1b    = (const float*)d_in[21];
    const float* h2w    = (const float*)d_in[22];
    const float* h2b    = (const float*)d_in[23];

    float* out = (float*)d_out;

    float*    h     = (float*)d_ws;                         // N x 64 f32
    float*    agg   = h + (size_t)N_NODES * 64;             // N x 64 f32
    ushort_t* msg16 = (ushort_t*)(agg + (size_t)N_NODES * 64); // N x 64 bf16
    ushort_t* hB16  = msg16 + (size_t)N_NODES * 64;         // N x 64 bf16
    int*      start = (int*)(hB16 + (size_t)N_NODES * 64);  // N + 1
    int*      bcnt  = start + N_NODES + 1;                  // 256 (pad)
    int*      bbase = bcnt + NBUCK;                         // 257 (pad to 288)
    int*      curA  = bbase + NBUCK + 32;                   // 256
    int*      csr   = curA + NBUCK;                         // E
    uint2*    pairs = (uint2*)agg;                          // alias: dead before gather writes agg
    ushort_t* hA16  = msg16;                                // alias: msg16 dead after gather1

    const int nb64 = (N_NODES + 63) / 64;                   // 1563 blocks for MLP kernels
    const int gatherBlocks = (N_NODES + 3) / 4;

    // ---- CSR build ----
    hipMemsetAsync(bcnt, 0, NBUCK * sizeof(int), stream);
    k_bhist<<<2048, 256, 0, stream>>>(rowIdx, bcnt);
    k_bscan256<<<1, 256, 0, stream>>>(bcnt, bbase, curA, start);
    k_bucketA<<<NBLK_A, 256, 0, stream>>>(rowIdx, colIdx, curA, pairs);
    k_bucketB<<<NBUCK, 256, 0, stream>>>(bbase, pairs, start, csr);

    // ---- input linear + layer0 message (fused) ----
    k_lin_msg<<<nb64, 256, 0, stream>>>(x, w_in, b_in,
                                        l0_m1w, l0_m1b, l0_m2w, l0_m2b, h, msg16);
    // ---- layer 0 aggregate; update + layer1 message (fused) ----
    k_gather<<<gatherBlocks, 256, 0, stream>>>(start, csr, msg16, agg);
    k_update_msg<<<nb64, 256, 0, stream>>>(h, agg, start,
                                           l0_u1w, l0_u1b, l0_u2w, l0_u2b,
                                           l1_m1w, l1_m1b, l1_m2w, l1_m2b, msg16);
    // ---- layer 1 aggregate; update + head precompute (fused) ----
    k_gather<<<gatherBlocks, 256, 0, stream>>>(start, csr, msg16, agg);
    k_update_headpre<<<nb64, 256, 0, stream>>>(h, agg, start,
                                               l1_u1w, l1_u1b, l1_u2w, l1_u2b,
                                               h1w, h1b, hA16, hB16);
    // ---- head ----
    k_head<<<4096, 256, 0, stream>>>(rowIdx, colIdx, hA16, hB16, h2w, h2b, out);
}